// Round 2
// baseline (2137.274 us; speedup 1.0000x reference)
//
#include <hip/hip_runtime.h>

#define BB   4
#define SS   1024
#define HH   16
#define DD   64
#define HID_ 1024
#define MM   4096          // B*S
#define RR   181
#define KMAX 90

// ---------------------------------------------------------------------------
// GEMM: C = A @ W^T + bias.  A [M=4096, K=1024] row-major, W [N=1024, K] row-major.
// Tile: 128(M) x 64(N), BK=16, 256 threads, 8x4 micro-tile per thread.
// blockIdx.z selects among up to 3 (A,W,bias,C) sets -> QKV in one launch.
// headMajor=1 writes C as [B, H, S, D] (for Q/K/V); else flat [M, N].
// ---------------------------------------------------------------------------
__global__ __launch_bounds__(256) void gemm_nt(
    const float* __restrict__ A0, const float* __restrict__ A1, const float* __restrict__ A2,
    const float* __restrict__ W0, const float* __restrict__ W1, const float* __restrict__ W2,
    const float* __restrict__ b0, const float* __restrict__ b1, const float* __restrict__ b2,
    float* __restrict__ C0, float* __restrict__ C1, float* __restrict__ C2,
    int headMajor)
{
    const int z = blockIdx.z;
    const float* A    = z == 0 ? A0 : (z == 1 ? A1 : A2);
    const float* W    = z == 0 ? W0 : (z == 1 ? W1 : W2);
    const float* bias = z == 0 ? b0 : (z == 1 ? b1 : b2);
    float*       C    = z == 0 ? C0 : (z == 1 ? C1 : C2);

    __shared__ float As[16][132];   // transposed: As[k][m]
    __shared__ float Ws[16][68];    // transposed: Ws[k][n]

    const int tid = threadIdx.x;
    const int mb = blockIdx.y * 128;
    const int nb = blockIdx.x * 64;
    const int tm = tid >> 4;        // 0..15 -> rows tm*8..+7
    const int tn = tid & 15;        // 0..15 -> cols tn*4..+3

    float acc[8][4];
#pragma unroll
    for (int i = 0; i < 8; ++i)
#pragma unroll
        for (int j = 0; j < 4; ++j) acc[i][j] = 0.f;

    for (int kb = 0; kb < HID_; kb += 16) {
        // stage A tile: 128x16 = 512 float4, 2 per thread (scatter-transpose)
#pragma unroll
        for (int ld = 0; ld < 2; ++ld) {
            int idx = tid + ld * 256;
            int row = idx >> 2;
            int c4  = (idx & 3) * 4;
            float4 v = *(const float4*)&A[(size_t)(mb + row) * HID_ + kb + c4];
            As[c4 + 0][row] = v.x; As[c4 + 1][row] = v.y;
            As[c4 + 2][row] = v.z; As[c4 + 3][row] = v.w;
        }
        // stage W tile: 64x16 = 256 float4, 1 per thread
        {
            int row = tid >> 2;
            int c4  = (tid & 3) * 4;
            float4 v = *(const float4*)&W[(size_t)(nb + row) * HID_ + kb + c4];
            Ws[c4 + 0][row] = v.x; Ws[c4 + 1][row] = v.y;
            Ws[c4 + 2][row] = v.z; Ws[c4 + 3][row] = v.w;
        }
        __syncthreads();
#pragma unroll
        for (int kk = 0; kk < 16; ++kk) {
            float a[8], w[4];
            *(float4*)&a[0] = *(const float4*)&As[kk][tm * 8];
            *(float4*)&a[4] = *(const float4*)&As[kk][tm * 8 + 4];
            *(float4*)&w[0] = *(const float4*)&Ws[kk][tn * 4];
#pragma unroll
            for (int i = 0; i < 8; ++i)
#pragma unroll
                for (int j = 0; j < 4; ++j)
                    acc[i][j] = fmaf(a[i], w[j], acc[i][j]);
        }
        __syncthreads();
    }

    const int n0 = nb + tn * 4;
    float4 bv = *(const float4*)&bias[n0];
#pragma unroll
    for (int i = 0; i < 8; ++i) {
        int m = mb + tm * 8 + i;
        float4 o;
        o.x = acc[i][0] + bv.x; o.y = acc[i][1] + bv.y;
        o.z = acc[i][2] + bv.z; o.w = acc[i][3] + bv.w;
        if (headMajor) {
            int b = m >> 10, s = m & 1023;
            int h = n0 >> 6, d = n0 & 63;
            *(float4*)&C[(((size_t)b * HH + h) * SS + s) * DD + d] = o;
        } else {
            *(float4*)&C[(size_t)m * HID_ + n0] = o;
        }
    }
}

// ---------------------------------------------------------------------------
// Fused attention: per block, one (b,h) and 16 q-rows; loop k in 32-tiles.
// energy = (Q.K + absE + Qr[clip]) / 8, masked; online softmax; acc += p*V;
// bucket sums of p by relative index -> r_x = buckets @ rel_v_emb at the end.
// Thread map: 256 thr = 16 rows x 16 lanes; lane owns 4 d's (d = lane*4+j).
// ---------------------------------------------------------------------------
__global__ __launch_bounds__(256) void attn_fused(
    const float* __restrict__ Qh, const float* __restrict__ Kh,
    const float* __restrict__ Vh, const int* __restrict__ mask,
    const float* __restrict__ absE, const float* __restrict__ relK,
    const float* __restrict__ relV, float* __restrict__ X)
{
    __shared__ float Qs[16][68];
    __shared__ float Ks[32][68];
    __shared__ float Vs[32][68];
    __shared__ float Qr[16][184];
    __shared__ float sB[16][184];
    __shared__ float Ps[16][36];

    const int tid  = threadIdx.x;
    const int ql   = tid >> 4;      // local q row 0..15
    const int lane = tid & 15;      // 0..15
    const int qb   = blockIdx.x * 16;
    const int bh   = blockIdx.y;    // b*16 + h
    const int b    = bh >> 4, h = bh & 15;
    const size_t rowbase = (size_t)bh * SS;
    const int qg = qb + ql;

    // Q tile: 16 rows x 64 = 256 float4, 1 per thread
    {
        int row = tid >> 4;
        int c4  = (tid & 15) * 4;
        *(float4*)&Qs[row][c4] = *(const float4*)&Qh[(rowbase + qb + row) * DD + c4];
    }
    __syncthreads();

    // Qr[q][r] = Q[q,:] . rel_k_emb[r,:]  (same 16-lane group -> wave-ordered)
    for (int r = lane; r < RR; r += 16) {
        float dot = 0.f;
#pragma unroll
        for (int d4 = 0; d4 < DD; d4 += 4) {
            float4 qv = *(const float4*)&Qs[ql][d4];
            float4 rv = *(const float4*)&relK[r * DD + d4];
            dot = fmaf(qv.x, rv.x, dot); dot = fmaf(qv.y, rv.y, dot);
            dot = fmaf(qv.z, rv.z, dot); dot = fmaf(qv.w, rv.w, dot);
        }
        Qr[ql][r] = dot;
        sB[ql][r] = 0.f;
    }

    float m = -1e30f, l = 0.f;
    float acc0 = 0.f, acc1 = 0.f, acc2 = 0.f, acc3 = 0.f;

    for (int kt = 0; kt < SS; kt += 32) {
        __syncthreads();   // previous tile fully consumed
        // stage K,V tiles: 32x64 = 512 float4 each; 2 per thread each
#pragma unroll
        for (int ld = 0; ld < 2; ++ld) {
            int idx = tid + ld * 256;
            int row = idx >> 4;
            int c4  = (idx & 15) * 4;
            *(float4*)&Ks[row][c4] = *(const float4*)&Kh[(rowbase + kt + row) * DD + c4];
            *(float4*)&Vs[row][c4] = *(const float4*)&Vh[(rowbase + kt + row) * DD + c4];
        }
        __syncthreads();

        float e[2];
#pragma unroll
        for (int half = 0; half < 2; ++half) {
            int kl = lane + half * 16;
            int kg = kt + kl;
            float dot = 0.f;
#pragma unroll
            for (int d4 = 0; d4 < DD; d4 += 4) {
                float4 qv = *(const float4*)&Qs[ql][d4];
                float4 kv = *(const float4*)&Ks[kl][d4];
                dot = fmaf(qv.x, kv.x, dot); dot = fmaf(qv.y, kv.y, dot);
                dot = fmaf(qv.z, kv.z, dot); dot = fmaf(qv.w, kv.w, dot);
            }
            int rel = kg - qg;
            rel = rel < -KMAX ? -KMAX : (rel > KMAX ? KMAX : rel);
            float en = (dot + absE[((size_t)h * SS + qg) * SS + kg] + Qr[ql][rel + KMAX]) * 0.125f;
            if (mask[((size_t)b * SS + qg) * SS + kg] == 0) en = -1e10f;
            e[half] = en;
        }

        // row max / sum across the 16 lanes of this row
        float tmax = fmaxf(e[0], e[1]);
#pragma unroll
        for (int off = 8; off; off >>= 1) tmax = fmaxf(tmax, __shfl_xor(tmax, off, 16));
        float mnew = fmaxf(m, tmax);
        float f  = __expf(m - mnew);
        float p0 = __expf(e[0] - mnew);
        float p1 = __expf(e[1] - mnew);
        float ps = p0 + p1;
#pragma unroll
        for (int off = 8; off; off >>= 1) ps += __shfl_xor(ps, off, 16);
        l = l * f + ps;
        m = mnew;
        acc0 *= f; acc1 *= f; acc2 *= f; acc3 *= f;

        // rescale buckets (own row only; same 16 lanes -> wave-ordered), then add
        for (int r = lane; r < RR; r += 16) sB[ql][r] *= f;
        int r0 = kt + lane - qg;      r0 = r0 < -KMAX ? -KMAX : (r0 > KMAX ? KMAX : r0);
        int r1 = kt + lane + 16 - qg; r1 = r1 < -KMAX ? -KMAX : (r1 > KMAX ? KMAX : r1);
        atomicAdd(&sB[ql][r0 + KMAX], p0);
        atomicAdd(&sB[ql][r1 + KMAX], p1);
        Ps[ql][lane]      = p0;
        Ps[ql][lane + 16] = p1;

        // acc += p * V   (Ps row written by own wave -> ordered; Vs synced above)
#pragma unroll 8
        for (int kk = 0; kk < 32; ++kk) {
            float p = Ps[ql][kk];
            float4 vv = *(const float4*)&Vs[kk][lane * 4];
            acc0 = fmaf(p, vv.x, acc0); acc1 = fmaf(p, vv.y, acc1);
            acc2 = fmaf(p, vv.z, acc2); acc3 = fmaf(p, vv.w, acc3);
        }
    }

    // r_x = buckets @ rel_v_emb, normalize, store x[b, q, h*64+d]
    float rx0 = 0.f, rx1 = 0.f, rx2 = 0.f, rx3 = 0.f;
    for (int r = 0; r < RR; ++r) {
        float s = sB[ql][r];
        float4 rv = *(const float4*)&relV[r * DD + lane * 4];
        rx0 = fmaf(s, rv.x, rx0); rx1 = fmaf(s, rv.y, rx1);
        rx2 = fmaf(s, rv.z, rx2); rx3 = fmaf(s, rv.w, rx3);
    }
    float inv = 1.f / l;
    float4 o;
    o.x = (acc0 + rx0) * inv; o.y = (acc1 + rx1) * inv;
    o.z = (acc2 + rx2) * inv; o.w = (acc3 + rx3) * inv;
    *(float4*)&X[((size_t)b * SS + qg) * HID_ + h * DD + lane * 4] = o;
}

// ---------------------------------------------------------------------------
extern "C" void kernel_launch(void* const* d_in, const int* in_sizes, int n_in,
                              void* d_out, int out_size, void* d_ws, size_t ws_size,
                              hipStream_t stream)
{
    const float* query = (const float*)d_in[0];
    const float* key   = (const float*)d_in[1];
    const float* value = (const float*)d_in[2];
    const int*   mask  = (const int*)  d_in[3];
    const float* absE  = (const float*)d_in[4];
    const float* Wq    = (const float*)d_in[5];
    const float* bq    = (const float*)d_in[6];
    const float* Wk    = (const float*)d_in[7];
    const float* bk    = (const float*)d_in[8];
    const float* Wv    = (const float*)d_in[9];
    const float* bv    = (const float*)d_in[10];
    const float* Wo    = (const float*)d_in[11];
    const float* bo    = (const float*)d_in[12];
    const float* relK  = (const float*)d_in[13];
    const float* relV  = (const float*)d_in[14];
    float* out = (float*)d_out;

    float* ws = (float*)d_ws;
    const size_t SZ = (size_t)MM * HID_;   // 4M floats
    float* Qh = ws;
    float* Kh = ws + SZ;
    float* Vh = ws + 2 * SZ;
    float* X  = ws + 3 * SZ;

    dim3 blk(256);

    // QKV projections: one batched launch (gridDim.z = 3) -> 1536 blocks
    dim3 qkvgrid(HID_ / 64, MM / 128, 3);  // (16, 32, 3)
    hipLaunchKernelGGL(gemm_nt, qkvgrid, blk, 0, stream,
                       query, key, value,
                       Wq, Wk, Wv,
                       bq, bk, bv,
                       Qh, Kh, Vh, 1);

    dim3 agrid(SS / 16, BB * HH);          // (64, 64)
    hipLaunchKernelGGL(attn_fused, agrid, blk, 0, stream,
                       Qh, Kh, Vh, mask, absE, relK, relV, X);

    // output projection: X @ Wo^T + bo -> out
    dim3 ogrid(HID_ / 64, MM / 128, 1);    // (16, 32, 1)
    hipLaunchKernelGGL(gemm_nt, ogrid, blk, 0, stream,
                       X, X, X,
                       Wo, Wo, Wo,
                       bo, bo, bo,
                       out, out, out, 0);
}

// Round 3
// 477.681 us; speedup vs baseline: 4.4743x; 4.4743x over previous
//
#include <hip/hip_runtime.h>

#define BB   4
#define SS   1024
#define HH   16
#define DD   64
#define HID_ 1024
#define MM   4096
#define RR   181
#define KMAX 90

typedef __attribute__((ext_vector_type(8))) short short8;
typedef __attribute__((ext_vector_type(8))) unsigned short ushort8;
typedef __attribute__((ext_vector_type(4))) float f32x4;

__device__ inline unsigned short f2b(float f) {
    unsigned int u = __float_as_uint(f);
    u = u + 0x7fffu + ((u >> 16) & 1u);      // RNE
    return (unsigned short)(u >> 16);
}
__device__ inline float b2f(unsigned short h) {
    return __uint_as_float(((unsigned int)h) << 16);
}
__device__ inline short8 pack8(float4 a, float4 b) {
    short8 r;
    r[0] = (short)f2b(a.x); r[1] = (short)f2b(a.y);
    r[2] = (short)f2b(a.z); r[3] = (short)f2b(a.w);
    r[4] = (short)f2b(b.x); r[5] = (short)f2b(b.y);
    r[6] = (short)f2b(b.z); r[7] = (short)f2b(b.w);
    return r;
}
#define MFMA(a, b, c) __builtin_amdgcn_mfma_f32_16x16x32_bf16((a), (b), (c), 0, 0, 0)

// ---------------------------------------------------------------------------
// MFMA GEMM: C = A @ W^T + bias. Tile 128x128, BK=32, 4 waves (2x2 of 64x64).
// AF32: A is f32 (converted in staging) else bf16. kind=0: bf16 out, z<2
// s-major [b,h,s,d], z==2 d-major [b,h,d,s]; kind=1: f32 flat [m][n].
// LDS strides 40 halfs (80B, bank-coeff 20 -> 2-way max).
// ---------------------------------------------------------------------------
template<int AF32>
__global__ __launch_bounds__(256) void gemm_mfma(
    const void* __restrict__ Ap0, const void* __restrict__ Ap1, const void* __restrict__ Ap2,
    const float* __restrict__ W0, const float* __restrict__ W1, const float* __restrict__ W2,
    const float* __restrict__ b0, const float* __restrict__ b1, const float* __restrict__ b2,
    void* __restrict__ Cp0, void* __restrict__ Cp1, void* __restrict__ Cp2,
    int kind)
{
    __shared__ ushort Asl[2][128][40];
    __shared__ ushort Wsl[2][128][40];

    const int z = blockIdx.z;
    const void*  Ap   = z == 0 ? Ap0 : (z == 1 ? Ap1 : Ap2);
    const float* W    = z == 0 ? W0  : (z == 1 ? W1  : W2);
    const float* bias = z == 0 ? b0  : (z == 1 ? b1  : b2);
    void*        Cp   = z == 0 ? Cp0 : (z == 1 ? Cp1 : Cp2);

    const int tid = threadIdx.x;
    const int wv = tid >> 6, lane = tid & 63, g = lane >> 4, ln = lane & 15;
    const int wm = wv >> 1, wn = wv & 1;
    const int m0 = blockIdx.y * 128, n0 = blockIdx.x * 128;
    const int srow = tid >> 1, sk0 = (tid & 1) * 16;

    f32x4 acc[4][4];
    f32x4 zz4 = {0.f, 0.f, 0.f, 0.f};
#pragma unroll
    for (int mi = 0; mi < 4; ++mi)
#pragma unroll
        for (int ni = 0; ni < 4; ++ni) acc[mi][ni] = zz4;

    auto STAGE = [&](int d, int t) {
        const int kb = t * 32;
        if (AF32) {
            const float* a = (const float*)Ap + (size_t)(m0 + srow) * HID_ + kb + sk0;
            *(short8*)&Asl[d][srow][sk0]     = pack8(*(const float4*)(a),     *(const float4*)(a + 4));
            *(short8*)&Asl[d][srow][sk0 + 8] = pack8(*(const float4*)(a + 8), *(const float4*)(a + 12));
        } else {
            const ushort* a = (const ushort*)Ap + (size_t)(m0 + srow) * HID_ + kb + sk0;
            *(ushort8*)&Asl[d][srow][sk0]     = *(const ushort8*)(a);
            *(ushort8*)&Asl[d][srow][sk0 + 8] = *(const ushort8*)(a + 8);
        }
        const float* w = W + (size_t)(n0 + srow) * HID_ + kb + sk0;
        *(short8*)&Wsl[d][srow][sk0]     = pack8(*(const float4*)(w),     *(const float4*)(w + 4));
        *(short8*)&Wsl[d][srow][sk0 + 8] = pack8(*(const float4*)(w + 8), *(const float4*)(w + 12));
    };

    STAGE(0, 0);
    for (int t = 0; t < 32; ++t) {
        __syncthreads();
        if (t + 1 < 32) STAGE((t + 1) & 1, t + 1);
        const int cur = t & 1;
        short8 af[4], wf[4];
#pragma unroll
        for (int mi = 0; mi < 4; ++mi) af[mi] = *(const short8*)&Asl[cur][64 * wm + 16 * mi + ln][8 * g];
#pragma unroll
        for (int ni = 0; ni < 4; ++ni) wf[ni] = *(const short8*)&Wsl[cur][64 * wn + 16 * ni + ln][8 * g];
#pragma unroll
        for (int mi = 0; mi < 4; ++mi)
#pragma unroll
            for (int ni = 0; ni < 4; ++ni)
                acc[mi][ni] = MFMA(af[mi], wf[ni], acc[mi][ni]);
    }

#pragma unroll
    for (int ni = 0; ni < 4; ++ni) {
        const int n_g = n0 + 64 * wn + 16 * ni + ln;
        const float bv = bias[n_g];
#pragma unroll
        for (int mi = 0; mi < 4; ++mi) {
#pragma unroll
            for (int rr = 0; rr < 4; ++rr) {
                const int m_g = m0 + 64 * wm + 16 * mi + 4 * g + rr;
                const float v = acc[mi][ni][rr] + bv;
                if (kind == 1) {
                    ((float*)Cp)[(size_t)m_g * HID_ + n_g] = v;
                } else {
                    const int bb = m_g >> 10, s = m_g & 1023, hh = n_g >> 6, dd = n_g & 63;
                    ushort* C = (ushort*)Cp;
                    if (z == 2) C[(((size_t)bb * HH + hh) * DD + dd) * SS + s] = f2b(v);  // V d-major
                    else        C[(((size_t)bb * HH + hh) * SS + s) * DD + dd] = f2b(v);  // Q/K s-major
                }
            }
        }
    }
}

// ---------------------------------------------------------------------------
// Fused MFMA attention. Per block: one (b,h), 64 q-rows (4 waves x 16).
// Single-pass online softmax. KVBLK=32 double-buffered. Shaw rel-V handled
// via: interior buckets are single-assignment (store raw energy bf16, exp
// after final max known), clip buckets accumulate in registers; then one
// 64x192 @ 192x64 MFMA adds r_x straight into the PV accumulator.
// ---------------------------------------------------------------------------
__global__ __launch_bounds__(256) void attn_mfma(
    const ushort* __restrict__ Qh, const ushort* __restrict__ Kh,
    const ushort* __restrict__ Vh, const int* __restrict__ mask,
    const float* __restrict__ absE, const float* __restrict__ relK,
    const float* __restrict__ relV, ushort* __restrict__ X)
{
    __shared__ ushort Kb[2][32][72];   // [k-local][d], stride 72 -> 2-way banks
    __shared__ ushort Vt[2][64][40];   // [d][k-local]
    __shared__ ushort QrV[64][200];    // phase 1: Qr[qloc][r]; phase 2: relV^T[d][delta]
    __shared__ ushort sB[64][200];     // in-band energies -> probabilities
    __shared__ ushort Ps[4][16][40];   // per-wave P tile round-trip
    __shared__ float  m_lds[64];

    const int tid = threadIdx.x;
    const int w = tid >> 6, lane = tid & 63, g = lane >> 4, ln = lane & 15;
    const int qb = blockIdx.x * 64;
    const int bh = blockIdx.y, b = bh >> 4, h = bh & 15;
    const size_t base = (size_t)bh * SS * DD;

    // Q fragments (A-operand rows = ln within wave strip), 2 k-chunks of d
    short8 qf0, qf1;
    {
        const ushort* qp = Qh + base + (size_t)(qb + 16 * w + ln) * DD + 8 * g;
        qf0 = *(const short8*)(qp);
        qf1 = *(const short8*)(qp + 32);
    }

    {   // zero sB (cols >=181 must stay 0 for the K=192 MFMA)
        ushort8 zz = {0, 0, 0, 0, 0, 0, 0, 0};
        for (int i = tid; i < 1600; i += 256) ((ushort8*)&sB[0][0])[i] = zz;
    }

    // Qr[qloc][r] = Q . relK[r] via MFMA (B-frags straight from global f32)
#pragma unroll 1
    for (int nt = 0; nt < 12; ++nt) {
        const int r = 16 * nt + ln;
        short8 bf0, bf1;
        if (r < RR) {
            const float* rp = relK + r * DD + 8 * g;
            bf0 = pack8(*(const float4*)(rp),      *(const float4*)(rp + 4));
            bf1 = pack8(*(const float4*)(rp + 32), *(const float4*)(rp + 36));
        } else {
            short8 zz = {0, 0, 0, 0, 0, 0, 0, 0}; bf0 = zz; bf1 = zz;
        }
        f32x4 c = {0.f, 0.f, 0.f, 0.f};
        c = MFMA(qf0, bf0, c);
        c = MFMA(qf1, bf1, c);
#pragma unroll
        for (int rr = 0; rr < 4; ++rr)
            QrV[16 * w + 4 * g + rr][r] = f2b(c[rr]);
    }
    __syncthreads();

    auto STAGEKV = [&](int d, int t) {
        const int kt = t * 32;
        {   // K: thread -> (k-row tid>>3, 8 d's)
            const int kl = tid >> 3, d0 = (tid & 7) * 8;
            *(ushort8*)&Kb[d][kl][d0] = *(const ushort8*)(Kh + base + (size_t)(kt + kl) * DD + d0);
        }
        {   // V^T: thread -> (d-row tid>>2, 8 k's); Vh is d-major
            const int dv = tid >> 2, k0 = (tid & 3) * 8;
            *(ushort8*)&Vt[d][dv][k0] = *(const ushort8*)(Vh + base + (size_t)dv * SS + kt + k0);
        }
    };

    f32x4 acc[4];  // [nt over d][rr]
    f32x4 zz4 = {0.f, 0.f, 0.f, 0.f};
#pragma unroll
    for (int nt = 0; nt < 4; ++nt) acc[nt] = zz4;
    float mrow[4], lrow[4], Pl[4], Pr[4];
#pragma unroll
    for (int rr = 0; rr < 4; ++rr) { mrow[rr] = -3.0e38f; lrow[rr] = 0.f; Pl[rr] = 0.f; Pr[rr] = 0.f; }

    const int qrow0 = qb + 16 * w + 4 * g;
    const float* aeBase = absE + ((size_t)h * SS + qrow0) * SS;
    const int*   mkBase = mask + ((size_t)b * SS + qrow0) * SS;

    STAGEKV(0, 0);
    for (int t = 0; t < 32; ++t) {
        __syncthreads();
        if (t + 1 < 32) STAGEKV((t + 1) & 1, t + 1);
        const int cur = t & 1;
        const int kt = t * 32;

        // QK^T: 2 col-tiles x 2 k-chunks
        f32x4 s0 = zz4, s1 = zz4;
        {
            short8 k00 = *(const short8*)&Kb[cur][ln][8 * g];
            short8 k01 = *(const short8*)&Kb[cur][ln][8 * g + 32];
            short8 k10 = *(const short8*)&Kb[cur][16 + ln][8 * g];
            short8 k11 = *(const short8*)&Kb[cur][16 + ln][8 * g + 32];
            s0 = MFMA(qf0, k00, s0); s0 = MFMA(qf1, k01, s0);
            s1 = MFMA(qf0, k10, s1); s1 = MFMA(qf1, k11, s1);
        }

        float e0[4], e1[4];
#pragma unroll
        for (int rr = 0; rr < 4; ++rr) {
            const int q = qrow0 + rr;
            const size_t ro = (size_t)rr * SS + kt + ln;
            int r0 = kt + ln - q;      r0 = r0 < -KMAX ? -KMAX : (r0 > KMAX ? KMAX : r0);
            int r1 = kt + 16 + ln - q; r1 = r1 < -KMAX ? -KMAX : (r1 > KMAX ? KMAX : r1);
            float v0 = (s0[rr] + aeBase[ro]      + b2f(QrV[16 * w + 4 * g + rr][r0 + KMAX])) * 0.125f;
            float v1 = (s1[rr] + aeBase[ro + 16] + b2f(QrV[16 * w + 4 * g + rr][r1 + KMAX])) * 0.125f;
            if (mkBase[ro] == 0)      v0 = -1e10f;
            if (mkBase[ro + 16] == 0) v1 = -1e10f;
            e0[rr] = v0; e1[rr] = v1;
        }

#pragma unroll
        for (int rr = 0; rr < 4; ++rr) {
            float tmax = fmaxf(e0[rr], e1[rr]);
            tmax = fmaxf(tmax, __shfl_xor(tmax, 1));
            tmax = fmaxf(tmax, __shfl_xor(tmax, 2));
            tmax = fmaxf(tmax, __shfl_xor(tmax, 4));
            tmax = fmaxf(tmax, __shfl_xor(tmax, 8));
            const float mnew = fmaxf(mrow[rr], tmax);
            const float f = __expf(mrow[rr] - mnew);
            mrow[rr] = mnew;
            const float p0 = __expf(e0[rr] - mnew);
            const float p1 = __expf(e1[rr] - mnew);
            float psum = p0 + p1;
            psum += __shfl_xor(psum, 1);
            psum += __shfl_xor(psum, 2);
            psum += __shfl_xor(psum, 4);
            psum += __shfl_xor(psum, 8);
            lrow[rr] = lrow[rr] * f + psum;
            acc[0][rr] *= f; acc[1][rr] *= f; acc[2][rr] *= f; acc[3][rr] *= f;
            Pl[rr] *= f; Pr[rr] *= f;

            const int q = qrow0 + rr;
            const int d0 = kt + ln - q + KMAX;
            const int d1 = kt + 16 + ln - q + KMAX;
            if (d0 <= 0)        Pl[rr] += p0;
            else if (d0 >= 180) Pr[rr] += p0;
            else                sB[16 * w + 4 * g + rr][d0] = f2b(e0[rr]);  // raw energy
            if (d1 <= 0)        Pl[rr] += p1;
            else if (d1 >= 180) Pr[rr] += p1;
            else                sB[16 * w + 4 * g + rr][d1] = f2b(e1[rr]);
            Ps[w][4 * g + rr][ln]      = f2b(p0);
            Ps[w][4 * g + rr][16 + ln] = f2b(p1);
        }

        // PV (Ps written/read by own wave only; Vt guarded by loop barrier)
        {
            short8 pa = *(const short8*)&Ps[w][ln][8 * g];
#pragma unroll
            for (int nt = 0; nt < 4; ++nt) {
                short8 vb = *(const short8*)&Vt[cur][16 * nt + ln][8 * g];
                acc[nt] = MFMA(pa, vb, acc[nt]);
            }
        }
    }

    // finalize row stats: m to LDS, clip-bucket sums into sB cols 0/180
#pragma unroll
    for (int rr = 0; rr < 4; ++rr) {
        float pl = Pl[rr], pr = Pr[rr];
        pl += __shfl_xor(pl, 1); pl += __shfl_xor(pl, 2); pl += __shfl_xor(pl, 4); pl += __shfl_xor(pl, 8);
        pr += __shfl_xor(pr, 1); pr += __shfl_xor(pr, 2); pr += __shfl_xor(pr, 4); pr += __shfl_xor(pr, 8);
        if (ln == 0) {
            m_lds[16 * w + 4 * g + rr] = mrow[rr];
            sB[16 * w + 4 * g + rr][0]   = f2b(pl);
            sB[16 * w + 4 * g + rr][180] = f2b(pr);
        }
    }
    __syncthreads();

    {   // zero QrV for the relV^T phase (cols>=181 must be 0)
        ushort8 zz = {0, 0, 0, 0, 0, 0, 0, 0};
        for (int i = tid; i < 1600; i += 256) ((ushort8*)&QrV[0][0])[i] = zz;
    }
    // exp-pass: in-band energies -> probabilities with the final max
    for (int idx = tid; idx < 12800; idx += 256) {
        const int row = idx / 200;
        const int col = idx - row * 200;
        if (col >= 1 && col <= 179) {
            const int k = qb + row + col - KMAX;   // k = q + (col-90)
            float p = 0.f;
            if (k >= 0 && k < SS) {
                const float e = b2f(((const ushort*)&sB[0][0])[idx]);
                p = __expf(fminf(e - m_lds[row], 0.f));
            }
            ((ushort*)&sB[0][0])[idx] = f2b(p);
        }
    }
    __syncthreads();
    // stage relV^T into QrV: QrV[d][delta]
    for (int i = tid; i < RR * 16; i += 256) {
        const int dl = i >> 4, d0 = (i & 15) * 4;
        const float4 v = *(const float4*)&relV[dl * DD + d0];
        QrV[d0][dl]     = f2b(v.x); QrV[d0 + 1][dl] = f2b(v.y);
        QrV[d0 + 2][dl] = f2b(v.z); QrV[d0 + 3][dl] = f2b(v.w);
    }
    __syncthreads();

    // r_x: acc += sB[64x192] @ relV[192x64]
#pragma unroll 1
    for (int c = 0; c < 6; ++c) {
        short8 a = *(const short8*)&sB[16 * w + ln][8 * g + 32 * c];
#pragma unroll
        for (int nt = 0; nt < 4; ++nt) {
            short8 bb = *(const short8*)&QrV[16 * nt + ln][8 * g + 32 * c];
            acc[nt] = MFMA(a, bb, acc[nt]);
        }
    }

    // epilogue: x = acc / l  -> X bf16 flat [b*s][h*64+d]
#pragma unroll
    for (int rr = 0; rr < 4; ++rr) {
        const float inv = 1.f / lrow[rr];
        const int q = qrow0 + rr;
#pragma unroll
        for (int nt = 0; nt < 4; ++nt) {
            X[((size_t)b * SS + q) * HID_ + h * DD + 16 * nt + ln] = f2b(acc[nt][rr] * inv);
        }
    }
}

// ---------------------------------------------------------------------------
extern "C" void kernel_launch(void* const* d_in, const int* in_sizes, int n_in,
                              void* d_out, int out_size, void* d_ws, size_t ws_size,
                              hipStream_t stream)
{
    const float* query = (const float*)d_in[0];
    const float* key   = (const float*)d_in[1];
    const float* value = (const float*)d_in[2];
    const int*   mask  = (const int*)  d_in[3];
    const float* absE  = (const float*)d_in[4];
    const float* Wq    = (const float*)d_in[5];
    const float* bq    = (const float*)d_in[6];
    const float* Wk    = (const float*)d_in[7];
    const float* bk    = (const float*)d_in[8];
    const float* Wv    = (const float*)d_in[9];
    const float* bv    = (const float*)d_in[10];
    const float* Wo    = (const float*)d_in[11];
    const float* bo    = (const float*)d_in[12];
    const float* relK  = (const float*)d_in[13];
    const float* relV  = (const float*)d_in[14];
    float* out = (float*)d_out;

    ushort* ws = (ushort*)d_ws;
    const size_t SZ = (size_t)MM * HID_;
    ushort* Qh = ws;            // bf16 [b,h,s,d]
    ushort* Kh = ws + SZ;       // bf16 [b,h,s,d]
    ushort* Vh = ws + 2 * SZ;   // bf16 [b,h,d,s]
    ushort* Xb = ws + 3 * SZ;   // bf16 [b*s][h*64+d]

    dim3 blk(256);
    hipLaunchKernelGGL((gemm_mfma<1>), dim3(8, 32, 3), blk, 0, stream,
                       (const void*)query, (const void*)key, (const void*)value,
                       Wq, Wk, Wv, bq, bk, bv,
                       (void*)Qh, (void*)Kh, (void*)Vh, 0);

    hipLaunchKernelGGL(attn_mfma, dim3(16, 64), blk, 0, stream,
                       Qh, Kh, Vh, mask, absE, relK, relV, Xb);

    hipLaunchKernelGGL((gemm_mfma<0>), dim3(8, 32, 1), blk, 0, stream,
                       (const void*)Xb, (const void*)Xb, (const void*)Xb,
                       Wo, Wo, Wo, bo, bo, bo,
                       (void*)out, (void*)out, (void*)out, 1);
}

// Round 8
// 456.229 us; speedup vs baseline: 4.6847x; 1.0470x over previous
//
#include <hip/hip_runtime.h>

#define BB   4
#define SS   1024
#define HH   16
#define DD   64
#define HID_ 1024
#define MM   4096
#define RR   181
#define KMAX 90

typedef __attribute__((ext_vector_type(8))) short short8;
typedef __attribute__((ext_vector_type(8))) unsigned short ushort8;
typedef __attribute__((ext_vector_type(4))) float f32x4;

__device__ inline unsigned short f2b(float f) {
    unsigned int u = __float_as_uint(f);
    u = u + 0x7fffu + ((u >> 16) & 1u);      // RNE
    return (unsigned short)(u >> 16);
}
__device__ inline float b2f(unsigned short h) {
    return __uint_as_float(((unsigned int)h) << 16);
}
__device__ inline unsigned int pk2(float a, float b) {
    return (unsigned int)f2b(a) | ((unsigned int)f2b(b) << 16);
}
__device__ inline short8 pack8(float4 a, float4 b) {
    short8 r;
    r[0] = (short)f2b(a.x); r[1] = (short)f2b(a.y);
    r[2] = (short)f2b(a.z); r[3] = (short)f2b(a.w);
    r[4] = (short)f2b(b.x); r[5] = (short)f2b(b.y);
    r[6] = (short)f2b(b.z); r[7] = (short)f2b(b.w);
    return r;
}
#define MFMA(a, b, c) __builtin_amdgcn_mfma_f32_16x16x32_bf16((a), (b), (c), 0, 0, 0)

// ---------------------------------------------------------------------------
// one-shot f32 -> bf16 conversion (q,k,v inputs + 4 weight matrices)
// ---------------------------------------------------------------------------
__global__ __launch_bounds__(256) void cvt7(
    const float* __restrict__ q, const float* __restrict__ k, const float* __restrict__ v,
    const float* __restrict__ wq, const float* __restrict__ wk,
    const float* __restrict__ wv, const float* __restrict__ wo,
    ushort* __restrict__ oq, ushort* __restrict__ ok, ushort* __restrict__ ov,
    ushort* __restrict__ owq, ushort* __restrict__ owk,
    ushort* __restrict__ owv, ushort* __restrict__ owo)
{
    const int y = blockIdx.y;
    const float* s; ushort* d; int n;
    switch (y) {
        case 0: s = q;  d = oq;  n = MM * HID_;   break;
        case 1: s = k;  d = ok;  n = MM * HID_;   break;
        case 2: s = v;  d = ov;  n = MM * HID_;   break;
        case 3: s = wq; d = owq; n = HID_ * HID_; break;
        case 4: s = wk; d = owk; n = HID_ * HID_; break;
        case 5: s = wv; d = owv; n = HID_ * HID_; break;
        default: s = wo; d = owo; n = HID_ * HID_; break;
    }
    const int i = (blockIdx.x * 256 + threadIdx.x) * 8;
    if (i < n) {
        float4 a = *(const float4*)&s[i];
        float4 b = *(const float4*)&s[i + 4];
        *(short8*)&d[i] = pack8(a, b);
    }
}

// ---------------------------------------------------------------------------
// MFMA GEMM: C = A @ W^T + bias. Tile 128x128, BK=32, 4 waves (2x2 of 64x64).
// AF32/WF32: staging converts from f32; else plain bf16 copies.
// kind==1: f32 flat out. kind==0: bf16; z<2 s-major [b,h,s,d], z==2 d-major
// [b,h,d,s] via LDS transpose epilogue (coalesced 128B row stores).
// ---------------------------------------------------------------------------
template<int AF32, int WF32>
__global__ __launch_bounds__(256) void gemm_mfma(
    const void* __restrict__ Ap0, const void* __restrict__ Ap1, const void* __restrict__ Ap2,
    const void* __restrict__ W0, const void* __restrict__ W1, const void* __restrict__ W2,
    const float* __restrict__ b0, const float* __restrict__ b1, const float* __restrict__ b2,
    void* __restrict__ Cp0, void* __restrict__ Cp1, void* __restrict__ Cp2,
    int kind)
{
    __shared__ ushort gsm[20480];                       // 40 KB: A(2x128x40) W(2x128x40); reused as CT[128][136]
#define ASL(dbf, r, c) gsm[(dbf) * 5120 + (r) * 40 + (c)]
#define WSL(dbf, r, c) gsm[10240 + (dbf) * 5120 + (r) * 40 + (c)]

    const int z = blockIdx.z;
    const void* Ap    = z == 0 ? Ap0 : (z == 1 ? Ap1 : Ap2);
    const void* Wp    = z == 0 ? W0  : (z == 1 ? W1  : W2);
    const float* bias = z == 0 ? b0  : (z == 1 ? b1  : b2);
    void* Cp          = z == 0 ? Cp0 : (z == 1 ? Cp1 : Cp2);

    const int tid = threadIdx.x;
    const int wv = tid >> 6, lane = tid & 63, g = lane >> 4, ln = lane & 15;
    const int wm = wv >> 1, wn = wv & 1;
    const int m0 = blockIdx.y * 128, n0 = blockIdx.x * 128;
    const int srow = tid >> 1, sk0 = (tid & 1) * 16;

    f32x4 acc[4][4];
    f32x4 zz4 = {0.f, 0.f, 0.f, 0.f};
#pragma unroll
    for (int mi = 0; mi < 4; ++mi)
#pragma unroll
        for (int ni = 0; ni < 4; ++ni) acc[mi][ni] = zz4;

    auto STAGE = [&](int d, int t) {
        const int kb = t * 32;
        if (AF32) {
            const float* a = (const float*)Ap + (size_t)(m0 + srow) * HID_ + kb + sk0;
            *(short8*)&ASL(d, srow, sk0)     = pack8(*(const float4*)(a),     *(const float4*)(a + 4));
            *(short8*)&ASL(d, srow, sk0 + 8) = pack8(*(const float4*)(a + 8), *(const float4*)(a + 12));
        } else {
            const ushort* a = (const ushort*)Ap + (size_t)(m0 + srow) * HID_ + kb + sk0;
            *(ushort8*)&ASL(d, srow, sk0)     = *(const ushort8*)(a);
            *(ushort8*)&ASL(d, srow, sk0 + 8) = *(const ushort8*)(a + 8);
        }
        if (WF32) {
            const float* w = (const float*)Wp + (size_t)(n0 + srow) * HID_ + kb + sk0;
            *(short8*)&WSL(d, srow, sk0)     = pack8(*(const float4*)(w),     *(const float4*)(w + 4));
            *(short8*)&WSL(d, srow, sk0 + 8) = pack8(*(const float4*)(w + 8), *(const float4*)(w + 12));
        } else {
            const ushort* w = (const ushort*)Wp + (size_t)(n0 + srow) * HID_ + kb + sk0;
            *(ushort8*)&WSL(d, srow, sk0)     = *(const ushort8*)(w);
            *(ushort8*)&WSL(d, srow, sk0 + 8) = *(const ushort8*)(w + 8);
        }
    };

    STAGE(0, 0);
    for (int t = 0; t < 32; ++t) {
        __syncthreads();
        if (t + 1 < 32) STAGE((t + 1) & 1, t + 1);
        const int cur = t & 1;
        short8 af[4], wf[4];
#pragma unroll
        for (int mi = 0; mi < 4; ++mi) af[mi] = *(const short8*)&ASL(cur, 64 * wm + 16 * mi + ln, 8 * g);
#pragma unroll
        for (int ni = 0; ni < 4; ++ni) wf[ni] = *(const short8*)&WSL(cur, 64 * wn + 16 * ni + ln, 8 * g);
#pragma unroll
        for (int mi = 0; mi < 4; ++mi)
#pragma unroll
            for (int ni = 0; ni < 4; ++ni)
                acc[mi][ni] = MFMA(af[mi], wf[ni], acc[mi][ni]);
    }

    if (kind == 1) {
#pragma unroll
        for (int ni = 0; ni < 4; ++ni) {
            const int n_g = n0 + 64 * wn + 16 * ni + ln;
            const float bv = bias[n_g];
#pragma unroll
            for (int mi = 0; mi < 4; ++mi)
#pragma unroll
                for (int rr = 0; rr < 4; ++rr) {
                    const int m_g = m0 + 64 * wm + 16 * mi + 4 * g + rr;
                    ((float*)Cp)[(size_t)m_g * HID_ + n_g] = acc[mi][ni][rr] + bv;
                }
        }
    } else if (z != 2) {                       // Q/K: bf16 s-major [b,h,s,d]
#pragma unroll
        for (int ni = 0; ni < 4; ++ni) {
            const int n_g = n0 + 64 * wn + 16 * ni + ln;
            const float bv = bias[n_g];
            const int hh = n_g >> 6, dd = n_g & 63;
#pragma unroll
            for (int mi = 0; mi < 4; ++mi)
#pragma unroll
                for (int rr = 0; rr < 4; ++rr) {
                    const int m_g = m0 + 64 * wm + 16 * mi + 4 * g + rr;
                    const int bb = m_g >> 10, s = m_g & 1023;
                    ((ushort*)Cp)[(((size_t)bb * HH + hh) * SS + s) * DD + dd] =
                        f2b(acc[mi][ni][rr] + bv);
                }
        }
    } else {                                   // V: bf16 d-major [b,h,d,s] via LDS transpose
        __syncthreads();
#pragma unroll
        for (int ni = 0; ni < 4; ++ni) {
            const int n_l = 64 * wn + 16 * ni + ln;
            const float bv = bias[n0 + n_l];
#pragma unroll
            for (int mi = 0; mi < 4; ++mi)
#pragma unroll
                for (int rr = 0; rr < 4; ++rr) {
                    const int m_l = 64 * wm + 16 * mi + 4 * g + rr;
                    gsm[n_l * 136 + m_l] = f2b(acc[mi][ni][rr] + bv);
                }
        }
        __syncthreads();
        const int r = tid >> 1, hf = tid & 1;
        const int n_g = n0 + r, hh = n_g >> 6, dd = n_g & 63;
        const int bb = m0 >> 10, s0g = (m0 & 1023) + 64 * hf;
        ushort* dst = (ushort*)Cp + (((size_t)bb * HH + hh) * DD + dd) * SS + s0g;
        const ushort* src = &gsm[r * 136 + 64 * hf];
#pragma unroll
        for (int i = 0; i < 8; ++i)
            *(ushort8*)&dst[8 * i] = *(const ushort8*)&src[8 * i];
    }
#undef ASL
#undef WSL
}

// ---------------------------------------------------------------------------
// Fused attention, swapped-QK layout: S^T = mfma(K,Q) puts every energy of
// q-row (16w+ln) in lane (g,ln) -> lane-local softmax stats (defer-max THR=8),
// vector absE/mask loads, K/V frags global->reg double-buffered (no barriers
// in the main loop). Shaw rel-V: interior buckets single-assignment (raw
// energy to sB, exp'd after final max), clip buckets in registers; one
// 64x192 @ 192x64 MFMA folds r_x into the PV accumulator.
// ---------------------------------------------------------------------------
struct TileRegs {
    short8 kf00, kf01, kf10, kf11;
    short8 vf0, vf1, vf2, vf3;
    float4 ae0, ae1;
    int4   mk0, mk1;
};

__global__ __launch_bounds__(256) void attn2(
    const ushort* __restrict__ Qh, const ushort* __restrict__ Kh,
    const ushort* __restrict__ Vh, const int* __restrict__ mask,
    const float* __restrict__ absE, const float* __restrict__ relK,
    const float* __restrict__ relV, ushort* __restrict__ X)
{
    __shared__ ushort QrV[64][200];          // phase1: Qr[q][r]; phase2: relV^T[d][delta]
    __shared__ ushort sB[64][200];           // raw energies -> probabilities (cols 0/180 = clip sums)
    __shared__ unsigned int Ps32[4][16][20]; // per-wave P tile (bf16 pairs)
    __shared__ float m_lds[64];

    const int tid = threadIdx.x;
    const int w = tid >> 6, lane = tid & 63, g = lane >> 4, ln = lane & 15;
    const int qb = blockIdx.x * 64;
    const int bh = blockIdx.y, b = bh >> 4, h = bh & 15;
    const size_t base = (size_t)bh * SS * DD;
    const int strow = 16 * w + ln;           // this lane's q (local)
    const int q_stat = qb + strow;           // this lane's q (global)
    const int qrow0 = qb + 16 * w + 4 * g;   // acc rows base (+rr)

    // Q fragments
    short8 qf0, qf1;
    {
        const ushort* qp = Qh + base + (size_t)q_stat * DD + 8 * g;
        qf0 = *(const short8*)(qp);
        qf1 = *(const short8*)(qp + 32);
    }

    // zero own strip of sB (wave-private rows)
    {
        ushort8 zz = {0, 0, 0, 0, 0, 0, 0, 0};
        for (int i = lane; i < 400; i += 64)
            *(ushort8*)&sB[16 * w + i / 25][(i % 25) * 8] = zz;
    }

    // Qr[q][r] = Q . relK[r] via MFMA (writes wave-private rows)
#pragma unroll 1
    for (int nt = 0; nt < 12; ++nt) {
        const int r = 16 * nt + ln;
        short8 bf0, bf1;
        if (r < RR) {
            const float* rp = relK + r * DD + 8 * g;
            bf0 = pack8(*(const float4*)(rp),      *(const float4*)(rp + 4));
            bf1 = pack8(*(const float4*)(rp + 32), *(const float4*)(rp + 36));
        } else {
            short8 zz = {0, 0, 0, 0, 0, 0, 0, 0}; bf0 = zz; bf1 = zz;
        }
        f32x4 c = {0.f, 0.f, 0.f, 0.f};
        c = MFMA(qf0, bf0, c);
        c = MFMA(qf1, bf1, c);
#pragma unroll
        for (int rr = 0; rr < 4; ++rr)
            QrV[16 * w + 4 * g + rr][r] = f2b(c[rr]);
    }

    const float* aeBase = absE + ((size_t)h * SS + q_stat) * SS;
    const int*   mkBase = mask + ((size_t)b * SS + q_stat) * SS;

    f32x4 zz4 = {0.f, 0.f, 0.f, 0.f};
    f32x4 acc0 = zz4, acc1 = zz4, acc2 = zz4, acc3 = zz4;
    float mst = -3.0e38f, lst = 0.f, Plc = 0.f, Prc = 0.f;

    auto LOAD = [&](TileRegs& R, int t) {
        const int kt = 32 * t;
        const ushort* kp = Kh + base + (size_t)(kt + ln) * DD + 8 * g;
        R.kf00 = *(const short8*)(kp);
        R.kf01 = *(const short8*)(kp + 32);
        R.kf10 = *(const short8*)(kp + 16 * DD);
        R.kf11 = *(const short8*)(kp + 16 * DD + 32);
        const ushort* vp = Vh + base + (size_t)ln * SS + kt + 8 * g;
        R.vf0 = *(const short8*)(vp);
        R.vf1 = *(const short8*)(vp + 16 * SS);
        R.vf2 = *(const short8*)(vp + 32 * SS);
        R.vf3 = *(const short8*)(vp + 48 * SS);
        const float* ap = aeBase + kt + 4 * g;
        R.ae0 = *(const float4*)(ap);
        R.ae1 = *(const float4*)(ap + 16);
        const int* mp = mkBase + kt + 4 * g;
        R.mk0 = *(const int4*)(mp);
        R.mk1 = *(const int4*)(mp + 16);
    };

    auto COMP = [&](const TileRegs& R, int t) {
        const int kt = 32 * t;
        f32x4 s0 = zz4, s1 = zz4;
        s0 = MFMA(R.kf00, qf0, s0); s0 = MFMA(R.kf01, qf1, s0);
        s1 = MFMA(R.kf10, qf0, s1); s1 = MFMA(R.kf11, qf1, s1);

        const int db0 = kt + 4 * g - q_stat + KMAX;   // delta of (s0, rr=0)
        float e0[4], e1[4];
#pragma unroll
        for (int rr = 0; rr < 4; ++rr) {
            int dc0 = db0 + rr;      dc0 = dc0 < 0 ? 0 : (dc0 > 180 ? 180 : dc0);
            int dc1 = db0 + 16 + rr; dc1 = dc1 < 0 ? 0 : (dc1 > 180 ? 180 : dc1);
            float v0 = (s0[rr] + (&R.ae0.x)[rr] + b2f(QrV[strow][dc0])) * 0.125f;
            float v1 = (s1[rr] + (&R.ae1.x)[rr] + b2f(QrV[strow][dc1])) * 0.125f;
            if ((&R.mk0.x)[rr] == 0) v0 = -1e10f;
            if ((&R.mk1.x)[rr] == 0) v1 = -1e10f;
            e0[rr] = v0; e1[rr] = v1;
        }

        float tmax = fmaxf(fmaxf(fmaxf(e0[0], e0[1]), fmaxf(e0[2], e0[3])),
                           fmaxf(fmaxf(e1[0], e1[1]), fmaxf(e1[2], e1[3])));
        tmax = fmaxf(tmax, __shfl_xor(tmax, 16));
        tmax = fmaxf(tmax, __shfl_xor(tmax, 32));
        if (__any(tmax > mst + 8.f)) {                 // defer-max: rare path
            const float mn = fmaxf(mst, tmax);
            const float f = __expf(mst - mn);
            mst = mn; lst *= f; Plc *= f; Prc *= f;
#pragma unroll
            for (int rr = 0; rr < 4; ++rr) {
                const float fa = __shfl(f, 4 * g + rr);
                acc0[rr] *= fa; acc1[rr] *= fa; acc2[rr] *= fa; acc3[rr] *= fa;
            }
        }

        float p0[4], p1[4], ps = 0.f;
#pragma unroll
        for (int rr = 0; rr < 4; ++rr) {
            p0[rr] = __expf(e0[rr] - mst);
            p1[rr] = __expf(e1[rr] - mst);
            ps += p0[rr] + p1[rr];
        }
        ps += __shfl_xor(ps, 16);
        ps += __shfl_xor(ps, 32);
        lst += ps;

#pragma unroll
        for (int rr = 0; rr < 4; ++rr) {
            const int dd0 = db0 + rr, dd1 = db0 + 16 + rr;
            if (dd0 <= 0)        Plc += p0[rr];
            else if (dd0 >= 180) Prc += p0[rr];
            else                 sB[strow][dd0] = f2b(e0[rr]);
            if (dd1 <= 0)        Plc += p1[rr];
            else if (dd1 >= 180) Prc += p1[rr];
            else                 sB[strow][dd1] = f2b(e1[rr]);
        }

        Ps32[w][ln][2 * g]         = pk2(p0[0], p0[1]);
        Ps32[w][ln][2 * g + 1]     = pk2(p0[2], p0[3]);
        Ps32[w][ln][8 + 2 * g]     = pk2(p1[0], p1[1]);
        Ps32[w][ln][8 + 2 * g + 1] = pk2(p1[2], p1[3]);

        short8 pa = *(const short8*)&Ps32[w][ln][4 * g];
        acc0 = MFMA(pa, R.vf0, acc0);
        acc1 = MFMA(pa, R.vf1, acc1);
        acc2 = MFMA(pa, R.vf2, acc2);
        acc3 = MFMA(pa, R.vf3, acc3);
    };

    TileRegs RA, RB;
    LOAD(RA, 0);
    for (int t = 0; t < 32; t += 2) {
        LOAD(RB, t + 1);
        COMP(RA, t);
        if (t + 2 < 32) LOAD(RA, t + 2);
        COMP(RB, t + 1);
    }

    // per-row finalize: clip sums + running max to LDS
    Plc += __shfl_xor(Plc, 16); Plc += __shfl_xor(Plc, 32);
    Prc += __shfl_xor(Prc, 16); Prc += __shfl_xor(Prc, 32);
    if (g == 0) {
        m_lds[strow] = mst;
        sB[strow][0]   = f2b(Plc);
        sB[strow][180] = f2b(Prc);
    }
    __syncthreads();

    // exp-pass: interior raw energies -> probabilities (final running max)
    for (int idx = tid; idx < 64 * 179; idx += 256) {
        const int row = idx / 179;
        const int col = 1 + idx - row * 179;
        const int k = qb + row + col - KMAX;
        float p = 0.f;
        if (k >= 0 && k < SS)
            p = __expf(b2f(sB[row][col]) - m_lds[row]);
        sB[row][col] = f2b(p);
    }
    // stage relV^T into QrV (Qr is dead)
    for (int i = tid; i < RR * 16; i += 256) {
        const int dl = i >> 4, d0 = (i & 15) * 4;
        const float4 v = *(const float4*)&relV[dl * DD + d0];
        QrV[d0 + 0][dl] = f2b(v.x); QrV[d0 + 1][dl] = f2b(v.y);
        QrV[d0 + 2][dl] = f2b(v.z); QrV[d0 + 3][dl] = f2b(v.w);
    }
    for (int i = tid; i < 64 * 19; i += 256)       // zero cols 181..199
        QrV[i / 19][181 + i % 19] = 0;
    __syncthreads();

    // r_x: acc += sB[64x192] @ relV^T[192x64]
#pragma unroll 1
    for (int c = 0; c < 6; ++c) {
        short8 a = *(const short8*)&sB[strow][8 * g + 32 * c];
        short8 b0 = *(const short8*)&QrV[ln][8 * g + 32 * c];
        short8 b1 = *(const short8*)&QrV[16 + ln][8 * g + 32 * c];
        short8 b2v = *(const short8*)&QrV[32 + ln][8 * g + 32 * c];
        short8 b3 = *(const short8*)&QrV[48 + ln][8 * g + 32 * c];
        acc0 = MFMA(a, b0, acc0);
        acc1 = MFMA(a, b1, acc1);
        acc2 = MFMA(a, b2v, acc2);
        acc3 = MFMA(a, b3, acc3);
    }

    // epilogue: x = acc / l -> bf16 [b*s][h*64+d]
#pragma unroll
    for (int rr = 0; rr < 4; ++rr) {
        const float li = __shfl(lst, 4 * g + rr);
        const float inv = 1.f / li;
        const int q = qrow0 + rr;
        ushort* xp = X + ((size_t)b * SS + q) * HID_ + h * DD + ln;
        xp[0]  = f2b(acc0[rr] * inv);
        xp[16] = f2b(acc1[rr] * inv);
        xp[32] = f2b(acc2[rr] * inv);
        xp[48] = f2b(acc3[rr] * inv);
    }
}

// ---------------------------------------------------------------------------
extern "C" void kernel_launch(void* const* d_in, const int* in_sizes, int n_in,
                              void* d_out, int out_size, void* d_ws, size_t ws_size,
                              hipStream_t stream)
{
    const float* query = (const float*)d_in[0];
    const float* key   = (const float*)d_in[1];
    const float* value = (const float*)d_in[2];
    const int*   mask  = (const int*)  d_in[3];
    const float* absE  = (const float*)d_in[4];
    const float* Wq    = (const float*)d_in[5];
    const float* bq    = (const float*)d_in[6];
    const float* Wk    = (const float*)d_in[7];
    const float* bk    = (const float*)d_in[8];
    const float* Wv    = (const float*)d_in[9];
    const float* bv    = (const float*)d_in[10];
    const float* Wo    = (const float*)d_in[11];
    const float* bo    = (const float*)d_in[12];
    const float* relK  = (const float*)d_in[13];
    const float* relV  = (const float*)d_in[14];
    float* out = (float*)d_out;

    ushort* ws = (ushort*)d_ws;
    const size_t SZ  = (size_t)MM * HID_;      // 4M halfs
    const size_t WSZ = (size_t)HID_ * HID_;    // 1M halfs
    dim3 blk(256);

    if (ws_size >= (size_t)58 * 1024 * 1024) {
        // big-ws path: pre-convert to bf16 once
        ushort* qc = ws;                 // also reused as Xb after QKV
        ushort* kc = ws + SZ;
        ushort* vc = ws + 2 * SZ;
        ushort* W16 = ws + 3 * SZ;       // Wq,Wk,Wv,Wo bf16
        ushort* Qh = ws + 3 * SZ + 4 * WSZ;
        ushort* Kh = Qh + SZ;
        ushort* Vh = Kh + SZ;
        ushort* Xb = qc;

        hipLaunchKernelGGL(cvt7, dim3(2048, 7), blk, 0, stream,
                           query, key, value, Wq, Wk, Wv, Wo,
                           qc, kc, vc, W16, W16 + WSZ, W16 + 2 * WSZ, W16 + 3 * WSZ);

        hipLaunchKernelGGL((gemm_mfma<0, 0>), dim3(8, 32, 3), blk, 0, stream,
                           (const void*)qc, (const void*)kc, (const void*)vc,
                           (const void*)W16, (const void*)(W16 + WSZ), (const void*)(W16 + 2 * WSZ),
                           bq, bk, bv, (void*)Qh, (void*)Kh, (void*)Vh, 0);

        hipLaunchKernelGGL(attn2, dim3(16, 64), blk, 0, stream,
                           Qh, Kh, Vh, mask, absE, relK, relV, Xb);

        hipLaunchKernelGGL((gemm_mfma<0, 0>), dim3(8, 32, 1), blk, 0, stream,
                           (const void*)Xb, (const void*)Xb, (const void*)Xb,
                           (const void*)(W16 + 3 * WSZ), (const void*)(W16 + 3 * WSZ), (const void*)(W16 + 3 * WSZ),
                           bo, bo, bo, (void*)out, (void*)out, (void*)out, 1);
    } else {
        // fallback (32 MB ws, R3-proven): convert inside GEMM staging
        ushort* Qh = ws;
        ushort* Kh = ws + SZ;
        ushort* Vh = ws + 2 * SZ;
        ushort* Xb = ws + 3 * SZ;

        hipLaunchKernelGGL((gemm_mfma<1, 1>), dim3(8, 32, 3), blk, 0, stream,
                           (const void*)query, (const void*)key, (const void*)value,
                           (const void*)Wq, (const void*)Wk, (const void*)Wv,
                           bq, bk, bv, (void*)Qh, (void*)Kh, (void*)Vh, 0);

        hipLaunchKernelGGL(attn2, dim3(16, 64), blk, 0, stream,
                           Qh, Kh, Vh, mask, absE, relK, relV, Xb);

        hipLaunchKernelGGL((gemm_mfma<0, 1>), dim3(8, 32, 1), blk, 0, stream,
                           (const void*)Xb, (const void*)Xb, (const void*)Xb,
                           (const void*)Wo, (const void*)Wo, (const void*)Wo,
                           bo, bo, bo, (void*)out, (void*)out, (void*)out, 1);
    }
}